// Round 17
// baseline (155.220 us; speedup 1.0000x reference)
//
#include <hip/hip_runtime.h>
#include <hip/hip_bf16.h>

typedef unsigned short ushort_t;
typedef __attribute__((ext_vector_type(8))) short short8;
typedef __attribute__((ext_vector_type(4))) float f32x4;

#define B_    4
#define T_    2048
#define D_    768
#define NH_   12
#define DH_   64
#define KDIM  768

__device__ __forceinline__ ushort_t f2bf(float f) {
  union { float f; unsigned u; } c; c.f = f;
  unsigned u = c.u;
  return (ushort_t)((u + 0x7FFFu + ((u >> 16) & 1u)) >> 16);
}

__device__ __forceinline__ unsigned cvt_pk_bf16(float lo, float hi) {
  unsigned r;
  asm("v_cvt_pk_bf16_f32 %0, %1, %2" : "=v"(r) : "v"(lo), "v"(hi));
  return r;
}

__device__ __forceinline__ void gload_lds16(const void* g, void* l) {
  __builtin_amdgcn_global_load_lds(
      (const __attribute__((address_space(1))) unsigned int*)g,
      (__attribute__((address_space(3))) unsigned int*)l, 16, 0, 0);
}

// ---------------------------------------------------------------- converts
__global__ void cvt_bf16_vec(const float* __restrict__ in,
                             ushort_t* __restrict__ out, int n4) {
  int i = blockIdx.x * blockDim.x + threadIdx.x;
  if (i >= n4) return;
  float4 v = ((const float4*)in)[i];
  ushort4 o;
  o.x = f2bf(v.x); o.y = f2bf(v.y); o.z = f2bf(v.z); o.w = f2bf(v.w);
  ((ushort4*)out)[i] = o;
}

// in [R][C] fp32 -> out [C][R] bf16
__global__ void transpose_cvt(const float* __restrict__ in,
                              ushort_t* __restrict__ out, int R, int C) {
  __shared__ float tile[32][33];
  int c0 = blockIdx.x * 32, r0 = blockIdx.y * 32;
  int tx = threadIdx.x, ty = threadIdx.y;
#pragma unroll
  for (int j = 0; j < 32; j += 8)
    tile[ty + j][tx] = in[(size_t)(r0 + ty + j) * C + c0 + tx];
  __syncthreads();
#pragma unroll
  for (int j = 0; j < 32; j += 8)
    out[(size_t)(c0 + ty + j) * R + r0 + tx] = f2bf(tile[tx][ty + j]);
}

// ---------------------------------------------------------------- GEMM core
// R15 mainloop: 256x128 tile, 8 waves (4m x 2n), BK=32, 3-buffer ring,
// counted vmcnt(3). R16 callers: XCD-locality block mapping (FETCH 70->34MB).
// Known limiter (R16 analysis): LDS pipe ~1400cyc/iter-round — structural.
__device__ __forceinline__ void gemm256_mainloop(
    const ushort_t* __restrict__ A, const ushort_t* __restrict__ BT,
    int m0, int n0, ushort_t* lds, f32x4 acc[4][4]) {
  const int t = threadIdx.x;           // 0..511
  const int l = t & 63;
  const int w = t >> 6;                // 0..7
  const int wm = w >> 1, wn = w & 1;
  const int g = l >> 4, qi = l & 15;
  const int cA0 = t, cA1 = t + 512, cB = t;
  const int rA0 = cA0 >> 2, rA1 = cA1 >> 2, rB = cB >> 2;
  const int sA0 = (cA0 & 3) ^ ((rA0 >> 2) & 3);
  const int sA1 = (cA1 & 3) ^ ((rA1 >> 2) & 3);
  const int sB = (cB & 3) ^ ((rB >> 2) & 3);
  const ushort_t* ga0 = A + (size_t)(m0 + rA0) * KDIM + (sA0 << 3);
  const ushort_t* ga1 = A + (size_t)(m0 + rA1) * KDIM + (sA1 << 3);
  const ushort_t* gb0 = BT + (size_t)(n0 + rB) * KDIM + (sB << 3);
  const int NK = KDIM / 32;
  const int rsw = (g ^ qi >> 2) << 3;

#pragma unroll
  for (int p = 0; p < 2; ++p) {
    ushort_t* lp = lds + p * 12288;
    int k0 = p * 32;
    gload_lds16(ga0 + k0, lp + w * 512);
    gload_lds16(ga1 + k0, lp + 4096 + w * 512);
    gload_lds16(gb0 + k0, lp + 8192 + w * 512);
  }

  int kb = 0;  // ring index = kk % 3
  for (int kk = 0; kk < NK; ++kk) {
    if (kk < NK - 1) {
      asm volatile("s_waitcnt vmcnt(3)" ::: "memory");
    } else {
      asm volatile("s_waitcnt vmcnt(0)" ::: "memory");
    }
    __builtin_amdgcn_sched_barrier(0);
    __builtin_amdgcn_s_barrier();
    __builtin_amdgcn_sched_barrier(0);
    if (kk + 2 < NK) {
      int kb2 = kb + 2 >= 3 ? kb - 1 : kb + 2;
      ushort_t* lp = lds + kb2 * 12288;
      int k0 = (kk + 2) * 32;
      gload_lds16(ga0 + k0, lp + w * 512);
      gload_lds16(ga1 + k0, lp + 4096 + w * 512);
      gload_lds16(gb0 + k0, lp + 8192 + w * 512);
    }
    ushort_t* lb = lds + kb * 12288;
    short8 af[4], bfv[4];
#pragma unroll
    for (int mt = 0; mt < 4; ++mt)
      af[mt] = *(const short8*)&lb[(wm * 64 + mt * 16 + qi) * 32 + rsw];
#pragma unroll
    for (int nt = 0; nt < 4; ++nt)
      bfv[nt] = *(const short8*)&lb[8192 + (wn * 64 + nt * 16 + qi) * 32 + rsw];
#pragma unroll
    for (int mt = 0; mt < 4; ++mt)
#pragma unroll
      for (int nt = 0; nt < 4; ++nt)
        acc[mt][nt] = __builtin_amdgcn_mfma_f32_16x16x32_bf16(
            af[mt], bfv[nt], acc[mt][nt], 0, 0, 0);
    kb = kb + 1 >= 3 ? 0 : kb + 1;
  }
}

// GEMM1: XCD-locality mapping (R16-validated).
__global__ __launch_bounds__(512, 4) void gemm_qkv_kernel(
    const ushort_t* __restrict__ xbf, const ushort_t* __restrict__ wT,
    const float* __restrict__ bias, ushort_t* __restrict__ qbf,
    float* __restrict__ kout, float* __restrict__ vout,
    ushort_t* __restrict__ kbf, ushort_t* __restrict__ vtbf) {
  __shared__ ushort_t lds[36864];
  int bid = blockIdx.x;                 // 576 = 8 XCDs x 4 mgroups x 18
  int xcd = bid & 7;
  int local = bid >> 3;                 // 0..71
  int m0 = (xcd * 4 + local / 18) << 8;
  int n0 = (local % 18) << 7;
  f32x4 acc[4][4];
  f32x4 zero = {0.f, 0.f, 0.f, 0.f};
#pragma unroll
  for (int a = 0; a < 4; ++a)
#pragma unroll
    for (int b = 0; b < 4; ++b) acc[a][b] = zero;
  gemm256_mainloop(xbf, wT, m0, n0, lds, acc);

  const float QSC = 0.125f * 1.44269504089f;
  const int l = threadIdx.x & 63, w = threadIdx.x >> 6;
  const int wm = w >> 1, wn = w & 1;
  const int sec = n0 / 768;
  const int b = m0 >> 11;
  const int tt_base = (m0 & 2047) + wm * 64;
#pragma unroll
  for (int nt = 0; nt < 4; ++nt) {
    int n = n0 + wn * 64 + nt * 16 + (l & 15);
    float bv = bias[n];
    int nn = n - sec * 768;
    int h = nn >> 6, dh = nn & 63;
    size_t head_base = ((size_t)(b * NH_ + h) * T_);
#pragma unroll
    for (int mt = 0; mt < 4; ++mt) {
      int tt0 = tt_base + mt * 16 + ((l >> 4) << 2);
      float vals[4];
#pragma unroll
      for (int r = 0; r < 4; ++r) vals[r] = acc[mt][nt][r] + bv;
      if (sec == 0) {
#pragma unroll
        for (int r = 0; r < 4; ++r)
          qbf[((head_base + tt0 + r) << 6) + dh] = f2bf(vals[r] * QSC);
      } else if (sec == 1) {
#pragma unroll
        for (int r = 0; r < 4; ++r) {
          size_t idx = ((head_base + tt0 + r) << 6) + dh;
          kout[idx] = vals[r];
          kbf[idx] = f2bf(vals[r]);
        }
      } else {
#pragma unroll
        for (int r = 0; r < 4; ++r)
          vout[((head_base + tt0 + r) << 6) + dh] = vals[r];
        ushort4 pk;
        pk.x = f2bf(vals[0]); pk.y = f2bf(vals[1]);
        pk.z = f2bf(vals[2]); pk.w = f2bf(vals[3]);
        *(ushort4*)&vtbf[((size_t)(b * NH_ + h) * DH_ + dh) * T_ + tt0] = pk;
      }
    }
  }
}

// GEMM2: XCD-locality mapping (192 = 8 x 4 x 6).
__global__ __launch_bounds__(512, 4) void gemm_proj_kernel(
    const ushort_t* __restrict__ abf, const ushort_t* __restrict__ wT,
    const float* __restrict__ bias, float* __restrict__ out) {
  __shared__ ushort_t lds[36864];
  int bid = blockIdx.x;
  int xcd = bid & 7;
  int local = bid >> 3;                 // 0..23
  int m0 = (xcd * 4 + local / 6) << 8;
  int n0 = (local % 6) << 7;
  f32x4 acc[4][4];
  f32x4 zero = {0.f, 0.f, 0.f, 0.f};
#pragma unroll
  for (int a = 0; a < 4; ++a)
#pragma unroll
    for (int b = 0; b < 4; ++b) acc[a][b] = zero;
  gemm256_mainloop(abf, wT, m0, n0, lds, acc);

  const int l = threadIdx.x & 63, w = threadIdx.x >> 6;
  const int wm = w >> 1, wn = w & 1;
#pragma unroll
  for (int nt = 0; nt < 4; ++nt) {
    int n = n0 + wn * 64 + nt * 16 + (l & 15);
    float bv = bias[n];
#pragma unroll
    for (int mt = 0; mt < 4; ++mt) {
#pragma unroll
      for (int r = 0; r < 4; ++r) {
        int m = m0 + wm * 64 + mt * 16 + ((l >> 4) << 2) + r;
        out[(size_t)m * D_ + n] = acc[mt][nt][r] + bv;
      }
    }
  }
}

// ---------------------------------------------------------------- attention
// R17: stripe-per-block. Block = one 128-row q-stripe (8 waves x 16 rows,
// contiguous); block s iterates KV tiles 0..2s+1 so ALL waves stay active
// until the diagonal (old hi/lo pairing idled lo waves ~65% of iters).
// Heavy-first dispatch; all 16 stripes of a bh pinned to one XCD so the
// 512KB KV set is L2-resident. sigma-permuted K rows (in-register P),
// ones-MFMA row-sum (R14-validated math).
__device__ __forceinline__ void strip_make_w(
    f32x4 s4[4], int gq, bool diag, int kvb, int g, short8 w[2]) {
  if (diag) {
#pragma unroll
    for (int nt = 0; nt < 4; ++nt) {
      int kb0 = kvb + ((nt >> 1) << 5) + (g << 3) + ((nt & 1) << 2);
#pragma unroll
      for (int r = 0; r < 4; ++r)
        if (kb0 + r > gq) s4[nt][r] = -1e30f;
    }
  }
  float p[4][4];
#pragma unroll
  for (int nt = 0; nt < 4; ++nt)
#pragma unroll
    for (int r = 0; r < 4; ++r) p[nt][r] = exp2f(s4[nt][r]);
#pragma unroll
  for (int k2 = 0; k2 < 2; ++k2) {
    union { unsigned u[4]; short8 s; } c;
    c.u[0] = cvt_pk_bf16(p[2 * k2][0], p[2 * k2][1]);
    c.u[1] = cvt_pk_bf16(p[2 * k2][2], p[2 * k2][3]);
    c.u[2] = cvt_pk_bf16(p[2 * k2 + 1][0], p[2 * k2 + 1][1]);
    c.u[3] = cvt_pk_bf16(p[2 * k2 + 1][2], p[2 * k2 + 1][3]);
    w[k2] = c.s;
  }
}

__global__ __launch_bounds__(512, 6) void attn_fwd_kernel(
    const ushort_t* __restrict__ qbf, const ushort_t* __restrict__ kbf,
    const ushort_t* __restrict__ vtbf, ushort_t* __restrict__ obf) {
  __shared__ ushort_t Kl[2][4096];
  __shared__ ushort_t Vt[2][4096];
  const int bid = blockIdx.x;
  const int xcd = bid & 7;
  const int idx = bid >> 3;             // 0..95
  const int s = 15 - (idx & 15);        // heavy stripes dispatched first
  const int bh = (idx >> 4) * 8 + xcd;  // bh pinned to one XCD (KV L2-local)
  const int lastB = 2 * s + 1;          // block loops tiles 0..lastB
  const int t = threadIdx.x, l = t & 63, w = t >> 6;  // w in 0..7
  const int g = l >> 4, qi = l & 15;
  const int qs0 = (s << 7) + (w << 4);  // wave's 16-row base
  const int lastMe = 2 * s + (w >= 4 ? 1 : 0);

  const ushort_t* Qb = qbf + (size_t)bh * T_ * DH_;
  const ushort_t* Kb = kbf + (size_t)bh * T_ * DH_;
  const ushort_t* Vb = vtbf + (size_t)bh * DH_ * T_;

  // staging: 512 threads cover one 64x64 tile; pre-swizzled source cols
  const int row0 = t >> 3, ch0 = t & 7;
  const int sw0 = (row0 & 3) | (((row0 >> 3) & 1) << 2);
  const ushort_t* gK0 = Kb + row0 * DH_ + ((ch0 ^ sw0) << 3);
  const ushort_t* gV0 = Vb + (size_t)row0 * T_ + ((ch0 ^ sw0) << 3);

  short8 aq[2];
  {
    const int qr = qs0 + qi;
    aq[0] = *(const short8*)&Qb[(size_t)qr * DH_ + (g << 3)];
    aq[1] = *(const short8*)&Qb[(size_t)qr * DH_ + (g << 3) + 32];
  }

  short8 ones;
#pragma unroll
  for (int j = 0; j < 8; ++j) ones[j] = (short)0x3F80;  // bf16 1.0

  f32x4 o[4], al;
  f32x4 zero = {0.f, 0.f, 0.f, 0.f};
#pragma unroll
  for (int nt = 0; nt < 4; ++nt) o[nt] = zero;
  al = zero;

  const int swzq = (qi & 3) | (((qi >> 2) & 1) << 2);
  const int swzv = (qi & 3) | (((qi >> 3) & 1) << 2);
  const int sigrow = ((qi >> 2) << 3) + (qi & 3);

  gload_lds16(gK0, &Kl[0][w * 512]);
  gload_lds16(gV0, &Vt[0][w * 512]);

  for (int kt = 0; kt <= lastB; ++kt) {
    const int buf = kt & 1;
    const int kvb = kt << 6;
    asm volatile("s_waitcnt vmcnt(0)" ::: "memory");
    __builtin_amdgcn_sched_barrier(0);
    __builtin_amdgcn_s_barrier();
    __builtin_amdgcn_sched_barrier(0);
    if (kt < lastB) {
      const int nx = kt + 1;
      gload_lds16(gK0 + (size_t)nx * 4096, &Kl[buf ^ 1][w * 512]);
      gload_lds16(gV0 + (size_t)nx * 64, &Vt[buf ^ 1][w * 512]);
    }
    if (kt <= lastMe) {
      // ---- S^T = (K_perm)(Q^T) ----
      f32x4 s4[4];
#pragma unroll
      for (int nt = 0; nt < 4; ++nt) s4[nt] = zero;
#pragma unroll
      for (int h2 = 0; h2 < 2; ++h2) {
        const int slotk = ((g + 4 * h2) ^ swzq) << 3;
#pragma unroll
        for (int nt = 0; nt < 4; ++nt) {
          int row = ((nt >> 1) << 5) + ((nt & 1) << 2) + sigrow;
          short8 bk = *(const short8*)&Kl[buf][(row << 6) + slotk];
          s4[nt] = __builtin_amdgcn_mfma_f32_16x16x32_bf16(bk, aq[h2],
                                                           s4[nt], 0, 0, 0);
        }
      }
      // ---- softmax in-register -> PV B-fragments ----
      short8 wfr[2];
      strip_make_w(s4, qs0 + qi, kvb + 63 > qs0, kvb, g, wfr);
      // ---- O^T += V^T P^T (+ l via ones-MFMA) ----
#pragma unroll
      for (int k2 = 0; k2 < 2; ++k2) {
        const int slotv = ((g + 4 * k2) ^ swzv) << 3;
#pragma unroll
        for (int nt = 0; nt < 4; ++nt) {
          short8 av = *(const short8*)&Vt[buf][((nt * 16 + qi) << 6) + slotv];
          o[nt] = __builtin_amdgcn_mfma_f32_16x16x32_bf16(av, wfr[k2], o[nt],
                                                          0, 0, 0);
        }
        al = __builtin_amdgcn_mfma_f32_16x16x32_bf16(ones, wfr[k2], al,
                                                     0, 0, 0);
      }
    }
  }

  const int b = bh / NH_, h = bh - b * NH_;
  {
    float inv = 1.f / al[0];
    int q = qs0 + qi;
    size_t rowb = (size_t)(b * T_ + q) * D_ + h * DH_;
#pragma unroll
    for (int nt = 0; nt < 4; ++nt) {
      ushort4 pk;
      pk.x = f2bf(o[nt][0] * inv);
      pk.y = f2bf(o[nt][1] * inv);
      pk.z = f2bf(o[nt][2] * inv);
      pk.w = f2bf(o[nt][3] * inv);
      *(ushort4*)&obf[rowb + nt * 16 + g * 4] = pk;
    }
  }
}

// ---------------------------------------------------------------- launch
extern "C" void kernel_launch(void* const* d_in, const int* in_sizes, int n_in,
                              void* d_out, int out_size, void* d_ws, size_t ws_size,
                              hipStream_t stream) {
  const float* x      = (const float*)d_in[0];
  const float* w_attn = (const float*)d_in[1];
  const float* b_attn = (const float*)d_in[2];
  const float* w_proj = (const float*)d_in[3];
  const float* b_proj = (const float*)d_in[4];

  float* out  = (float*)d_out;
  float* kout = out + (size_t)B_ * T_ * D_;
  float* vout = kout + (size_t)B_ * T_ * D_;

  char* ws = (char*)d_ws;
  ushort_t* xbf = (ushort_t*)(ws);                  // reused as abf
  ushort_t* wTa = (ushort_t*)(ws + 12582912);
  ushort_t* wTp = (ushort_t*)(ws + 16121856);
  ushort_t* qbf = (ushort_t*)(ws + 17301504);
  ushort_t* kbf = (ushort_t*)(ws + 29884416);
  ushort_t* vtbf = (ushort_t*)(ws + 42467328);
  ushort_t* abf = xbf;

  cvt_bf16_vec<<<6144, 256, 0, stream>>>(x, xbf, (B_ * T_ * D_) / 4);
  dim3 tb(32, 8);
  transpose_cvt<<<dim3(72, 24), tb, 0, stream>>>(w_attn, wTa, D_, 3 * D_);
  transpose_cvt<<<dim3(24, 24), tb, 0, stream>>>(w_proj, wTp, D_, D_);

  gemm_qkv_kernel<<<32 * 18, 512, 0, stream>>>(xbf, wTa, b_attn, qbf, kout, vout,
                                               kbf, vtbf);
  attn_fwd_kernel<<<768, 512, 0, stream>>>(qbf, kbf, vtbf, abf);
  gemm_proj_kernel<<<32 * 6, 512, 0, stream>>>(abf, wTp, b_proj, out);
}

// Round 18
// 131.845 us; speedup vs baseline: 1.1773x; 1.1773x over previous
//
#include <hip/hip_runtime.h>
#include <hip/hip_bf16.h>

typedef unsigned short ushort_t;
typedef __attribute__((ext_vector_type(8))) short short8;
typedef __attribute__((ext_vector_type(4))) float f32x4;

#define B_    4
#define T_    2048
#define D_    768
#define NH_   12
#define DH_   64
#define KDIM  768

__device__ __forceinline__ ushort_t f2bf(float f) {
  union { float f; unsigned u; } c; c.f = f;
  unsigned u = c.u;
  return (ushort_t)((u + 0x7FFFu + ((u >> 16) & 1u)) >> 16);
}

__device__ __forceinline__ unsigned cvt_pk_bf16(float lo, float hi) {
  unsigned r;
  asm("v_cvt_pk_bf16_f32 %0, %1, %2" : "=v"(r) : "v"(lo), "v"(hi));
  return r;
}

__device__ __forceinline__ void gload_lds16(const void* g, void* l) {
  __builtin_amdgcn_global_load_lds(
      (const __attribute__((address_space(1))) unsigned int*)g,
      (__attribute__((address_space(3))) unsigned int*)l, 16, 0, 0);
}

// ---------------------------------------------------------------- converts
__global__ void cvt_bf16_vec(const float* __restrict__ in,
                             ushort_t* __restrict__ out, int n4) {
  int i = blockIdx.x * blockDim.x + threadIdx.x;
  if (i >= n4) return;
  float4 v = ((const float4*)in)[i];
  ushort4 o;
  o.x = f2bf(v.x); o.y = f2bf(v.y); o.z = f2bf(v.z); o.w = f2bf(v.w);
  ((ushort4*)out)[i] = o;
}

// in [R][C] fp32 -> out [C][R] bf16
__global__ void transpose_cvt(const float* __restrict__ in,
                              ushort_t* __restrict__ out, int R, int C) {
  __shared__ float tile[32][33];
  int c0 = blockIdx.x * 32, r0 = blockIdx.y * 32;
  int tx = threadIdx.x, ty = threadIdx.y;
#pragma unroll
  for (int j = 0; j < 32; j += 8)
    tile[ty + j][tx] = in[(size_t)(r0 + ty + j) * C + c0 + tx];
  __syncthreads();
#pragma unroll
  for (int j = 0; j < 32; j += 8)
    out[(size_t)(c0 + ty + j) * R + r0 + tx] = f2bf(tile[tx][ty + j]);
}

// ---------------------------------------------------------------- GEMM core
// R15 mainloop: 256x128 tile, 8 waves (4m x 2n), BK=32, 3-buffer ring,
// counted vmcnt(3). R16 callers: XCD-locality block mapping (FETCH 70->34MB).
// Known limiter (R16 analysis): LDS pipe ~1400cyc/iter-round — structural.
__device__ __forceinline__ void gemm256_mainloop(
    const ushort_t* __restrict__ A, const ushort_t* __restrict__ BT,
    int m0, int n0, ushort_t* lds, f32x4 acc[4][4]) {
  const int t = threadIdx.x;           // 0..511
  const int l = t & 63;
  const int w = t >> 6;                // 0..7
  const int wm = w >> 1, wn = w & 1;
  const int g = l >> 4, qi = l & 15;
  const int cA0 = t, cA1 = t + 512, cB = t;
  const int rA0 = cA0 >> 2, rA1 = cA1 >> 2, rB = cB >> 2;
  const int sA0 = (cA0 & 3) ^ ((rA0 >> 2) & 3);
  const int sA1 = (cA1 & 3) ^ ((rA1 >> 2) & 3);
  const int sB = (cB & 3) ^ ((rB >> 2) & 3);
  const ushort_t* ga0 = A + (size_t)(m0 + rA0) * KDIM + (sA0 << 3);
  const ushort_t* ga1 = A + (size_t)(m0 + rA1) * KDIM + (sA1 << 3);
  const ushort_t* gb0 = BT + (size_t)(n0 + rB) * KDIM + (sB << 3);
  const int NK = KDIM / 32;
  const int rsw = (g ^ qi >> 2) << 3;

#pragma unroll
  for (int p = 0; p < 2; ++p) {
    ushort_t* lp = lds + p * 12288;
    int k0 = p * 32;
    gload_lds16(ga0 + k0, lp + w * 512);
    gload_lds16(ga1 + k0, lp + 4096 + w * 512);
    gload_lds16(gb0 + k0, lp + 8192 + w * 512);
  }

  int kb = 0;  // ring index = kk % 3
  for (int kk = 0; kk < NK; ++kk) {
    if (kk < NK - 1) {
      asm volatile("s_waitcnt vmcnt(3)" ::: "memory");
    } else {
      asm volatile("s_waitcnt vmcnt(0)" ::: "memory");
    }
    __builtin_amdgcn_sched_barrier(0);
    __builtin_amdgcn_s_barrier();
    __builtin_amdgcn_sched_barrier(0);
    if (kk + 2 < NK) {
      int kb2 = kb + 2 >= 3 ? kb - 1 : kb + 2;
      ushort_t* lp = lds + kb2 * 12288;
      int k0 = (kk + 2) * 32;
      gload_lds16(ga0 + k0, lp + w * 512);
      gload_lds16(ga1 + k0, lp + 4096 + w * 512);
      gload_lds16(gb0 + k0, lp + 8192 + w * 512);
    }
    ushort_t* lb = lds + kb * 12288;
    short8 af[4], bfv[4];
#pragma unroll
    for (int mt = 0; mt < 4; ++mt)
      af[mt] = *(const short8*)&lb[(wm * 64 + mt * 16 + qi) * 32 + rsw];
#pragma unroll
    for (int nt = 0; nt < 4; ++nt)
      bfv[nt] = *(const short8*)&lb[8192 + (wn * 64 + nt * 16 + qi) * 32 + rsw];
#pragma unroll
    for (int mt = 0; mt < 4; ++mt)
#pragma unroll
      for (int nt = 0; nt < 4; ++nt)
        acc[mt][nt] = __builtin_amdgcn_mfma_f32_16x16x32_bf16(
            af[mt], bfv[nt], acc[mt][nt], 0, 0, 0);
    kb = kb + 1 >= 3 ? 0 : kb + 1;
  }
}

// GEMM1: XCD-locality mapping (R16-validated).
__global__ __launch_bounds__(512, 4) void gemm_qkv_kernel(
    const ushort_t* __restrict__ xbf, const ushort_t* __restrict__ wT,
    const float* __restrict__ bias, ushort_t* __restrict__ qbf,
    float* __restrict__ kout, float* __restrict__ vout,
    ushort_t* __restrict__ kbf, ushort_t* __restrict__ vtbf) {
  __shared__ ushort_t lds[36864];
  int bid = blockIdx.x;                 // 576 = 8 XCDs x 4 mgroups x 18
  int xcd = bid & 7;
  int local = bid >> 3;                 // 0..71
  int m0 = (xcd * 4 + local / 18) << 8;
  int n0 = (local % 18) << 7;
  f32x4 acc[4][4];
  f32x4 zero = {0.f, 0.f, 0.f, 0.f};
#pragma unroll
  for (int a = 0; a < 4; ++a)
#pragma unroll
    for (int b = 0; b < 4; ++b) acc[a][b] = zero;
  gemm256_mainloop(xbf, wT, m0, n0, lds, acc);

  const float QSC = 0.125f * 1.44269504089f;
  const int l = threadIdx.x & 63, w = threadIdx.x >> 6;
  const int wm = w >> 1, wn = w & 1;
  const int sec = n0 / 768;
  const int b = m0 >> 11;
  const int tt_base = (m0 & 2047) + wm * 64;
#pragma unroll
  for (int nt = 0; nt < 4; ++nt) {
    int n = n0 + wn * 64 + nt * 16 + (l & 15);
    float bv = bias[n];
    int nn = n - sec * 768;
    int h = nn >> 6, dh = nn & 63;
    size_t head_base = ((size_t)(b * NH_ + h) * T_);
#pragma unroll
    for (int mt = 0; mt < 4; ++mt) {
      int tt0 = tt_base + mt * 16 + ((l >> 4) << 2);
      float vals[4];
#pragma unroll
      for (int r = 0; r < 4; ++r) vals[r] = acc[mt][nt][r] + bv;
      if (sec == 0) {
#pragma unroll
        for (int r = 0; r < 4; ++r)
          qbf[((head_base + tt0 + r) << 6) + dh] = f2bf(vals[r] * QSC);
      } else if (sec == 1) {
#pragma unroll
        for (int r = 0; r < 4; ++r) {
          size_t idx = ((head_base + tt0 + r) << 6) + dh;
          kout[idx] = vals[r];
          kbf[idx] = f2bf(vals[r]);
        }
      } else {
#pragma unroll
        for (int r = 0; r < 4; ++r)
          vout[((head_base + tt0 + r) << 6) + dh] = vals[r];
        ushort4 pk;
        pk.x = f2bf(vals[0]); pk.y = f2bf(vals[1]);
        pk.z = f2bf(vals[2]); pk.w = f2bf(vals[3]);
        *(ushort4*)&vtbf[((size_t)(b * NH_ + h) * DH_ + dh) * T_ + tt0] = pk;
      }
    }
  }
}

// GEMM2: XCD-locality mapping (192 = 8 x 4 x 6).
__global__ __launch_bounds__(512, 4) void gemm_proj_kernel(
    const ushort_t* __restrict__ abf, const ushort_t* __restrict__ wT,
    const float* __restrict__ bias, float* __restrict__ out) {
  __shared__ ushort_t lds[36864];
  int bid = blockIdx.x;
  int xcd = bid & 7;
  int local = bid >> 3;                 // 0..23
  int m0 = (xcd * 4 + local / 6) << 8;
  int n0 = (local % 6) << 7;
  f32x4 acc[4][4];
  f32x4 zero = {0.f, 0.f, 0.f, 0.f};
#pragma unroll
  for (int a = 0; a < 4; ++a)
#pragma unroll
    for (int b = 0; b < 4; ++b) acc[a][b] = zero;
  gemm256_mainloop(abf, wT, m0, n0, lds, acc);

  const int l = threadIdx.x & 63, w = threadIdx.x >> 6;
  const int wm = w >> 1, wn = w & 1;
#pragma unroll
  for (int nt = 0; nt < 4; ++nt) {
    int n = n0 + wn * 64 + nt * 16 + (l & 15);
    float bv = bias[n];
#pragma unroll
    for (int mt = 0; mt < 4; ++mt) {
#pragma unroll
      for (int r = 0; r < 4; ++r) {
        int m = m0 + wm * 64 + mt * 16 + ((l >> 4) << 2) + r;
        out[(size_t)m * D_ + n] = acc[mt][nt][r] + bv;
      }
    }
  }
}

// ---------------------------------------------------------------- attention
// R16-validated (REVERT of R17's stripe-per-block, which unbalanced block
// durations 2..32 iters and regressed 58->79us): balanced hi/lo pair strips
// (j, 31-j) -> every block = 33 compute wave-iters; 8 waves, 1 strip/wave;
// sigma-permuted K rows (in-register P); ones-MFMA row-sum; XCD swizzle.
__device__ __forceinline__ void strip_make_w(
    f32x4 s4[4], int gq, bool diag, int kvb, int g, short8 w[2]) {
  if (diag) {
#pragma unroll
    for (int nt = 0; nt < 4; ++nt) {
      int kb0 = kvb + ((nt >> 1) << 5) + (g << 3) + ((nt & 1) << 2);
#pragma unroll
      for (int r = 0; r < 4; ++r)
        if (kb0 + r > gq) s4[nt][r] = -1e30f;
    }
  }
  float p[4][4];
#pragma unroll
  for (int nt = 0; nt < 4; ++nt)
#pragma unroll
    for (int r = 0; r < 4; ++r) p[nt][r] = exp2f(s4[nt][r]);
#pragma unroll
  for (int k2 = 0; k2 < 2; ++k2) {
    union { unsigned u[4]; short8 s; } c;
    c.u[0] = cvt_pk_bf16(p[2 * k2][0], p[2 * k2][1]);
    c.u[1] = cvt_pk_bf16(p[2 * k2][2], p[2 * k2][3]);
    c.u[2] = cvt_pk_bf16(p[2 * k2 + 1][0], p[2 * k2 + 1][1]);
    c.u[3] = cvt_pk_bf16(p[2 * k2 + 1][2], p[2 * k2 + 1][3]);
    w[k2] = c.s;
  }
}

__global__ __launch_bounds__(512, 6) void attn_fwd_kernel(
    const ushort_t* __restrict__ qbf, const ushort_t* __restrict__ kbf,
    const ushort_t* __restrict__ vtbf, ushort_t* __restrict__ obf) {
  __shared__ ushort_t Kl[2][4096];
  __shared__ ushort_t Vt[2][4096];
  const int bid = blockIdx.x;
  const int swz = (bid & 7) * 96 + (bid >> 3);   // 768 blocks, 8 XCDs
  const int jp = swz & 15;
  const int bh = swz >> 4;
  const int qlo = jp << 6, qhi = (31 - jp) << 6;
  const int lastH = 31 - jp, lastL = jp;
  const int t = threadIdx.x, l = t & 63, w = t >> 6;  // w in 0..7
  const int g = l >> 4, qi = l & 15;
  const bool isHi = (w < 4);
  const int wc = isHi ? w : (w - 4);
  const int qs0 = (isHi ? qhi : qlo) + wc * 16;   // wave's 16-row base
  const int lastMe = isHi ? lastH : lastL;

  const ushort_t* Qb = qbf + (size_t)bh * T_ * DH_;
  const ushort_t* Kb = kbf + (size_t)bh * T_ * DH_;
  const ushort_t* Vb = vtbf + (size_t)bh * DH_ * T_;

  const int row0 = t >> 3, ch0 = t & 7;
  const int sw0 = (row0 & 3) | (((row0 >> 3) & 1) << 2);
  const ushort_t* gK0 = Kb + row0 * DH_ + ((ch0 ^ sw0) << 3);
  const ushort_t* gV0 = Vb + (size_t)row0 * T_ + ((ch0 ^ sw0) << 3);

  short8 aq[2];
  {
    const int qr = qs0 + qi;
    aq[0] = *(const short8*)&Qb[(size_t)qr * DH_ + (g << 3)];
    aq[1] = *(const short8*)&Qb[(size_t)qr * DH_ + (g << 3) + 32];
  }

  short8 ones;
#pragma unroll
  for (int j = 0; j < 8; ++j) ones[j] = (short)0x3F80;  // bf16 1.0

  f32x4 o[4], al;
  f32x4 zero = {0.f, 0.f, 0.f, 0.f};
#pragma unroll
  for (int nt = 0; nt < 4; ++nt) o[nt] = zero;
  al = zero;

  const int swzq = (qi & 3) | (((qi >> 2) & 1) << 2);
  const int swzv = (qi & 3) | (((qi >> 3) & 1) << 2);
  const int sigrow = ((qi >> 2) << 3) + (qi & 3);

  gload_lds16(gK0, &Kl[0][w * 512]);
  gload_lds16(gV0, &Vt[0][w * 512]);

  for (int kt = 0; kt <= lastH; ++kt) {
    const int buf = kt & 1;
    const int kvb = kt << 6;
    asm volatile("s_waitcnt vmcnt(0)" ::: "memory");
    __builtin_amdgcn_sched_barrier(0);
    __builtin_amdgcn_s_barrier();
    __builtin_amdgcn_sched_barrier(0);
    if (kt < lastH) {
      const int nx = kt + 1;
      gload_lds16(gK0 + (size_t)nx * 4096, &Kl[buf ^ 1][w * 512]);
      gload_lds16(gV0 + (size_t)nx * 64, &Vt[buf ^ 1][w * 512]);
    }
    if (kt <= lastMe) {
      f32x4 s4[4];
#pragma unroll
      for (int nt = 0; nt < 4; ++nt) s4[nt] = zero;
#pragma unroll
      for (int h2 = 0; h2 < 2; ++h2) {
        const int slotk = ((g + 4 * h2) ^ swzq) << 3;
#pragma unroll
        for (int nt = 0; nt < 4; ++nt) {
          int row = ((nt >> 1) << 5) + ((nt & 1) << 2) + sigrow;
          short8 bk = *(const short8*)&Kl[buf][(row << 6) + slotk];
          s4[nt] = __builtin_amdgcn_mfma_f32_16x16x32_bf16(bk, aq[h2],
                                                           s4[nt], 0, 0, 0);
        }
      }
      short8 wfr[2];
      strip_make_w(s4, qs0 + qi, kt == lastMe, kvb, g, wfr);
#pragma unroll
      for (int k2 = 0; k2 < 2; ++k2) {
        const int slotv = ((g + 4 * k2) ^ swzv) << 3;
#pragma unroll
        for (int nt = 0; nt < 4; ++nt) {
          short8 av = *(const short8*)&Vt[buf][((nt * 16 + qi) << 6) + slotv];
          o[nt] = __builtin_amdgcn_mfma_f32_16x16x32_bf16(av, wfr[k2], o[nt],
                                                          0, 0, 0);
        }
        al = __builtin_amdgcn_mfma_f32_16x16x32_bf16(ones, wfr[k2], al,
                                                     0, 0, 0);
      }
    }
  }

  const int b = bh / NH_, h = bh - b * NH_;
  {
    float inv = 1.f / al[0];
    int q = qs0 + qi;
    size_t rowb = (size_t)(b * T_ + q) * D_ + h * DH_;
#pragma unroll
    for (int nt = 0; nt < 4; ++nt) {
      ushort4 pk;
      pk.x = f2bf(o[nt][0] * inv);
      pk.y = f2bf(o[nt][1] * inv);
      pk.z = f2bf(o[nt][2] * inv);
      pk.w = f2bf(o[nt][3] * inv);
      *(ushort4*)&obf[rowb + nt * 16 + g * 4] = pk;
    }
  }
}

// ---------------------------------------------------------------- launch
extern "C" void kernel_launch(void* const* d_in, const int* in_sizes, int n_in,
                              void* d_out, int out_size, void* d_ws, size_t ws_size,
                              hipStream_t stream) {
  const float* x      = (const float*)d_in[0];
  const float* w_attn = (const float*)d_in[1];
  const float* b_attn = (const float*)d_in[2];
  const float* w_proj = (const float*)d_in[3];
  const float* b_proj = (const float*)d_in[4];

  float* out  = (float*)d_out;
  float* kout = out + (size_t)B_ * T_ * D_;
  float* vout = kout + (size_t)B_ * T_ * D_;

  char* ws = (char*)d_ws;
  ushort_t* xbf = (ushort_t*)(ws);                  // reused as abf
  ushort_t* wTa = (ushort_t*)(ws + 12582912);
  ushort_t* wTp = (ushort_t*)(ws + 16121856);
  ushort_t* qbf = (ushort_t*)(ws + 17301504);
  ushort_t* kbf = (ushort_t*)(ws + 29884416);
  ushort_t* vtbf = (ushort_t*)(ws + 42467328);
  ushort_t* abf = xbf;

  cvt_bf16_vec<<<6144, 256, 0, stream>>>(x, xbf, (B_ * T_ * D_) / 4);
  dim3 tb(32, 8);
  transpose_cvt<<<dim3(72, 24), tb, 0, stream>>>(w_attn, wTa, D_, 3 * D_);
  transpose_cvt<<<dim3(24, 24), tb, 0, stream>>>(w_proj, wTp, D_, D_);

  gemm_qkv_kernel<<<32 * 18, 512, 0, stream>>>(xbf, wTa, b_attn, qbf, kout, vout,
                                               kbf, vtbf);
  attn_fwd_kernel<<<768, 512, 0, stream>>>(qbf, kbf, vtbf, abf);
  gemm_proj_kernel<<<32 * 6, 512, 0, stream>>>(abf, wTp, b_proj, out);
}